// Round 5
// baseline (630.509 us; speedup 1.0000x reference)
//
#include <hip/hip_runtime.h>
#include <hip/hip_bf16.h>

// Problem constants
#define NNODES 100000
#define NEDGES 300000
#define FIN 128
#define HDIM 256
#define NLAYERS 3
#define MPAD 100096  // 1564 * 64 (row padding: grid.y covers MPAD/64 blocks)

typedef float f32x4 __attribute__((ext_vector_type(4)));
typedef short bf16x8 __attribute__((ext_vector_type(8)));

__device__ inline float bf2f(unsigned short u) {
    union { unsigned int i; float f; } v;
    v.i = ((unsigned int)u) << 16;
    return v.f;
}
__device__ inline unsigned short f2bf(float f) {  // RNE
    union { float f; unsigned int i; } v;
    v.f = f;
    return (unsigned short)((v.i + 0x7fffu + ((v.i >> 16) & 1u)) >> 16);
}

// A-fragment loaders: bf16 direct (16B) or fp32 (2x16B) + in-register pack
__device__ inline bf16x8 loadA(const unsigned short* p) {
    return *((const bf16x8*)p);
}
__device__ inline bf16x8 loadA(const float* p) {
    float4 lo = *((const float4*)p);
    float4 hi = *((const float4*)(p + 4));
    bf16x8 r;
    r[0] = (short)f2bf(lo.x); r[1] = (short)f2bf(lo.y);
    r[2] = (short)f2bf(lo.z); r[3] = (short)f2bf(lo.w);
    r[4] = (short)f2bf(hi.x); r[5] = (short)f2bf(hi.y);
    r[6] = (short)f2bf(hi.z); r[7] = (short)f2bf(hi.w);
    return r;
}

// ---------------------------------------------------------------------------
// Barrier-free LDS-free MFMA GEMM: C[M,256] = act(A[M,K] @ B[K,256] + bias)
// A: [.][K] (bf16 or fp32). Bt: bf16 [256][K] pre-transposed. bias fp32.
// Block = 4 waves = 64 rows x 256 cols; wave w = 64 rows x cols [w*64,w*64+64)
// via 4x4 of 16x16x32 MFMA. All operands straight from global: A-tile (32KB)
// is read once per block (4 waves hit L1/L2); B (<=131KB) is L2-resident.
// No __syncthreads, no LDS -> no barrier drain, free wave scheduling.
// ---------------------------------------------------------------------------
template <int K, typename AT, bool BIAS, bool RELU, bool OUTF32>
__global__ __launch_bounds__(256) void gemm_nolds_k(
    const AT* __restrict__ A, const unsigned short* __restrict__ Bt,
    const float* __restrict__ bias, void* __restrict__ C, int M) {
    const int lane = threadIdx.x & 63;
    const int wid = threadIdx.x >> 6;
    const int col0 = wid * 64;
    const int rowbase = blockIdx.y * 64;
    const int r15 = lane & 15;
    const int kq = lane >> 4;  // 0..3

    // Precompute row/col base pointers (rows clamped -> no OOB reads on input)
    const AT* aptr[4];
#pragma unroll
    for (int i = 0; i < 4; ++i) {
        int row = rowbase + i * 16 + r15;
        if (row > M - 1) row = M - 1;
        aptr[i] = A + (size_t)row * K + kq * 8;
    }
    const unsigned short* bptr[4];
#pragma unroll
    for (int j = 0; j < 4; ++j)
        bptr[j] = Bt + (size_t)(col0 + j * 16 + r15) * K + kq * 8;

    f32x4 acc[4][4] = {};
#pragma unroll
    for (int k0 = 0; k0 < K; k0 += 32) {
        bf16x8 af[4], bfr[4];
#pragma unroll
        for (int i = 0; i < 4; ++i) af[i] = loadA(aptr[i] + k0);
#pragma unroll
        for (int j = 0; j < 4; ++j) bfr[j] = *((const bf16x8*)(bptr[j] + k0));
#pragma unroll
        for (int i = 0; i < 4; ++i)
#pragma unroll
            for (int j = 0; j < 4; ++j)
                acc[i][j] = __builtin_amdgcn_mfma_f32_16x16x32_bf16(af[i], bfr[j], acc[i][j], 0, 0, 0);
    }

    // Epilogue: C/D layout col=lane&15, row=(lane>>4)*4+reg
#pragma unroll
    for (int i = 0; i < 4; ++i) {
#pragma unroll
        for (int reg = 0; reg < 4; ++reg) {
            int row = rowbase + i * 16 + (lane >> 4) * 4 + reg;
            if (row >= M) continue;
#pragma unroll
            for (int j = 0; j < 4; ++j) {
                int col = col0 + j * 16 + (lane & 15);
                float v = acc[i][j][reg];
                if (BIAS) v += bias[col];
                if (RELU) v = fmaxf(v, 0.0f);
                if (OUTF32)
                    ((float*)C)[(size_t)row * HDIM + col] = v;
                else
                    ((unsigned short*)C)[(size_t)row * HDIM + col] = f2bf(v);
            }
        }
    }
}

// ---------------------------------------------------------------------------
// Weight prep: W[nm][K][256] fp32 -> Wt[nm][256][K] bf16 (transpose+convert)
// ---------------------------------------------------------------------------
__global__ void wprep_k(const float* __restrict__ W, unsigned short* __restrict__ Wt,
                        int K, int total) {
    int i = blockIdx.x * blockDim.x + threadIdx.x;
    if (i >= total) return;
    int mat = i / (K * 256);
    int r = i - mat * (K * 256);
    int k = r >> 8, p = r & 255;
    Wt[(size_t)mat * K * 256 + (size_t)p * K + k] = f2bf(W[i]);
}

// ---------------------------------------------------------------------------
// CSR build utilities
// ---------------------------------------------------------------------------
__global__ void zero_k(unsigned* __restrict__ p, int n) {
    int i = blockIdx.x * blockDim.x + threadIdx.x;
    if (i < n) p[i] = 0u;
}

__global__ void count_k(const int* __restrict__ dst, unsigned* __restrict__ cnt, int E) {
    int e = blockIdx.x * blockDim.x + threadIdx.x;
    if (e < E) atomicAdd(&cnt[dst[e]], 1u);
}

__global__ void dinv_k(const unsigned* __restrict__ cnt, float* __restrict__ dinv, int N) {
    int i = blockIdx.x * blockDim.x + threadIdx.x;
    if (i < N) dinv[i] = 1.0f / sqrtf((float)(cnt[i] + 1u));  // +1 = self loop
}

__global__ __launch_bounds__(256) void scan1_k(const unsigned* __restrict__ cnt,
                                               int* __restrict__ rs,
                                               unsigned* __restrict__ blocksum, int N) {
    __shared__ unsigned tmp[256];
    int tid = threadIdx.x;
    int gid = blockIdx.x * 256 + tid;
    unsigned v = (gid < N) ? cnt[gid] : 0u;
    tmp[tid] = v;
    __syncthreads();
#pragma unroll
    for (int off = 1; off < 256; off <<= 1) {
        unsigned t = (tid >= off) ? tmp[tid - off] : 0u;
        __syncthreads();
        tmp[tid] += t;
        __syncthreads();
    }
    if (gid < N) rs[gid] = (int)(tmp[tid] - v);
    if (tid == 255) blocksum[blockIdx.x] = tmp[tid];
}

__global__ __launch_bounds__(512) void scan2_k(unsigned* __restrict__ blocksum, int nb) {
    __shared__ unsigned tmp[512];
    int tid = threadIdx.x;
    unsigned v = (tid < nb) ? blocksum[tid] : 0u;
    tmp[tid] = v;
    __syncthreads();
#pragma unroll
    for (int off = 1; off < 512; off <<= 1) {
        unsigned t = (tid >= off) ? tmp[tid - off] : 0u;
        __syncthreads();
        tmp[tid] += t;
        __syncthreads();
    }
    if (tid < nb) blocksum[tid] = tmp[tid] - v;
}

__global__ void scan3_k(int* __restrict__ rs, const unsigned* __restrict__ blocksum, int N, int E) {
    int gid = blockIdx.x * blockDim.x + threadIdx.x;
    if (gid < N) rs[gid] += (int)blocksum[gid >> 8];
    if (gid == 0) rs[N] = E;
}

__global__ void fill_k(const int* __restrict__ src, const int* __restrict__ dst,
                       const int* __restrict__ rs, unsigned* __restrict__ cursor,
                       const float* __restrict__ dinv,
                       int* __restrict__ srcs, float* __restrict__ ww, int E) {
    int e = blockIdx.x * blockDim.x + threadIdx.x;
    if (e >= E) return;
    int s = src[e], d = dst[e];
    int pos = rs[d] + (int)atomicAdd(&cursor[d], 1u);
    srcs[pos] = s;
    ww[pos] = dinv[s] * dinv[d];
}

// ---------------------------------------------------------------------------
// CSR gather-aggregate (bf16 m), fused self-loop + bias + ReLU.
// One wave per node; ushort4 (4 cols) per lane.
// ---------------------------------------------------------------------------
template <bool OUTF32>
__global__ __launch_bounds__(256) void gather_k(const int* __restrict__ rs,
                                                const int* __restrict__ srcs,
                                                const float* __restrict__ ww,
                                                const float* __restrict__ dinv,
                                                const unsigned short* __restrict__ m,
                                                const float* __restrict__ bias,
                                                void* __restrict__ out, int N) {
    int node = blockIdx.x * 4 + (threadIdx.x >> 6);
    int lane = threadIdx.x & 63;
    if (node >= N) return;
    int beg = rs[node], end = rs[node + 1];
    float d = dinv[node];
    float w0 = d * d;
    ushort4 u = ((const ushort4*)(m + (size_t)node * HDIM))[lane];
    float ax = bf2f(u.x) * w0, ay = bf2f(u.y) * w0, az = bf2f(u.z) * w0, aw = bf2f(u.w) * w0;
    for (int e = beg; e < end; ++e) {
        int s = srcs[e];
        float w = ww[e];
        ushort4 v = ((const ushort4*)(m + (size_t)s * HDIM))[lane];
        ax += bf2f(v.x) * w;
        ay += bf2f(v.y) * w;
        az += bf2f(v.z) * w;
        aw += bf2f(v.w) * w;
    }
    float4 b = ((const float4*)bias)[lane];
    ax = fmaxf(ax + b.x, 0.0f);
    ay = fmaxf(ay + b.y, 0.0f);
    az = fmaxf(az + b.z, 0.0f);
    aw = fmaxf(aw + b.w, 0.0f);
    if (OUTF32) {
        float4 o = {ax, ay, az, aw};
        ((float4*)out)[(size_t)node * 64 + lane] = o;
    } else {
        ushort4 o;
        o.x = f2bf(ax); o.y = f2bf(ay); o.z = f2bf(az); o.w = f2bf(aw);
        ((ushort4*)out)[(size_t)node * 64 + lane] = o;
    }
}

extern "C" void kernel_launch(void* const* d_in, const int* in_sizes, int n_in,
                              void* d_out, int out_size, void* d_ws, size_t ws_size,
                              hipStream_t stream) {
    const float* x  = (const float*)d_in[0];
    const int* ei   = (const int*)d_in[1];
    const float* w1 = (const float*)d_in[2];
    const float* b1 = (const float*)d_in[3];
    const float* w2 = (const float*)d_in[4];
    const float* b2 = (const float*)d_in[5];
    const float* gw = (const float*)d_in[6];
    const float* gb = (const float*)d_in[7];

    const int N = NNODES, E = NEDGES;
    const int* src = ei;
    const int* dst = ei + E;

    // Workspace layout (~158 MB)
    char* p = (char*)d_ws;
    unsigned short* h1  = (unsigned short*)p; p += (size_t)MPAD * HDIM * 2;  // 51.2 MB
    unsigned short* h   = (unsigned short*)p; p += (size_t)MPAD * HDIM * 2;
    unsigned short* m   = (unsigned short*)p; p += (size_t)MPAD * HDIM * 2;
    unsigned short* w1t = (unsigned short*)p; p += (size_t)FIN * HDIM * 2;
    unsigned short* w2t = (unsigned short*)p; p += (size_t)HDIM * HDIM * 2;
    unsigned short* gwt = (unsigned short*)p; p += (size_t)NLAYERS * HDIM * HDIM * 2;
    unsigned* cnt = (unsigned*)p;      p += (size_t)N * 4;
    float* dinv = (float*)p;           p += (size_t)N * 4;
    int* rs = (int*)p;                 p += (size_t)(N + 1) * 4 + 12;  // keep 16B align
    unsigned* blocksum = (unsigned*)p; p += 512 * 4;
    int* srcs = (int*)p;               p += (size_t)E * 4;
    float* wwt = (float*)p;            p += (size_t)E * 4;

    const int nb = (N + 255) / 256;             // 391
    const dim3 ggrid(1, MPAD / 64);             // 1564 blocks, 4 waves each

    // ---- Weight conversion ----
    wprep_k<<<(FIN * 256 + 255) / 256, 256, 0, stream>>>(w1, w1t, FIN, FIN * 256);
    wprep_k<<<(HDIM * 256 + 255) / 256, 256, 0, stream>>>(w2, w2t, HDIM, HDIM * 256);
    wprep_k<<<(NLAYERS * HDIM * 256 + 255) / 256, 256, 0, stream>>>(gw, gwt, HDIM, NLAYERS * HDIM * 256);

    // ---- CSR build ----
    zero_k<<<nb, 256, 0, stream>>>(cnt, N);
    count_k<<<(E + 255) / 256, 256, 0, stream>>>(dst, cnt, E);
    dinv_k<<<nb, 256, 0, stream>>>(cnt, dinv, N);
    scan1_k<<<nb, 256, 0, stream>>>(cnt, rs, blocksum, N);
    scan2_k<<<1, 512, 0, stream>>>(blocksum, nb);
    scan3_k<<<nb + 1, 256, 0, stream>>>(rs, blocksum, N, E);
    zero_k<<<nb, 256, 0, stream>>>(cnt, N);  // reuse as cursor
    fill_k<<<(E + 255) / 256, 256, 0, stream>>>(src, dst, rs, cnt, dinv, srcs, wwt, E);

    // ---- Encoder (xconv fused into first GEMM: fp32 A loads + pack) ----
    gemm_nolds_k<FIN, float, true, true, false><<<ggrid, 256, 0, stream>>>(x, w1t, b1, h1, N);
    gemm_nolds_k<HDIM, unsigned short, true, false, false><<<ggrid, 256, 0, stream>>>(h1, w2t, b2, h, N);

    // ---- GCN layers ----
    for (int l = 0; l < NLAYERS; ++l) {
        const unsigned short* wl = gwt + (size_t)l * HDIM * HDIM;
        const float* bl = gb + (size_t)l * HDIM;
        gemm_nolds_k<HDIM, unsigned short, false, false, false><<<ggrid, 256, 0, stream>>>(h, wl, nullptr, m, N);
        if (l < NLAYERS - 1)
            gather_k<false><<<(N + 3) / 4, 256, 0, stream>>>(rs, srcs, wwt, dinv, m, bl, h, N);
        else
            gather_k<true><<<(N + 3) / 4, 256, 0, stream>>>(rs, srcs, wwt, dinv, m, bl, d_out, N);
    }
}

// Round 6
// 601.786 us; speedup vs baseline: 1.0477x; 1.0477x over previous
//
#include <hip/hip_runtime.h>
#include <hip/hip_bf16.h>

// Problem constants
#define NNODES 100000
#define NEDGES 300000
#define FIN 128
#define HDIM 256
#define NLAYERS 3
#define MPAD 100096  // 1564 * 64

typedef float f32x4 __attribute__((ext_vector_type(4)));
typedef short bf16x8 __attribute__((ext_vector_type(8)));

__device__ inline float bf2f(unsigned short u) {
    union { unsigned int i; float f; } v;
    v.i = ((unsigned int)u) << 16;
    return v.f;
}
__device__ inline unsigned short f2bf(float f) {  // RNE
    union { float f; unsigned int i; } v;
    v.f = f;
    return (unsigned short)((v.i + 0x7fffu + ((v.i >> 16) & 1u)) >> 16);
}

// A-fragment loaders: bf16 direct (16B) or fp32 (2x16B) + in-register pack
__device__ inline bf16x8 loadA(const unsigned short* p) {
    return *((const bf16x8*)p);
}
__device__ inline bf16x8 loadA(const float* p) {
    float4 lo = *((const float4*)p);
    float4 hi = *((const float4*)(p + 4));
    bf16x8 r;
    r[0] = (short)f2bf(lo.x); r[1] = (short)f2bf(lo.y);
    r[2] = (short)f2bf(lo.z); r[3] = (short)f2bf(lo.w);
    r[4] = (short)f2bf(hi.x); r[5] = (short)f2bf(hi.y);
    r[6] = (short)f2bf(hi.z); r[7] = (short)f2bf(hi.w);
    return r;
}

// ---------------------------------------------------------------------------
// Barrier-free LDS-free MFMA GEMM with explicit register double-buffering.
// C[M,256] = act(A[M,K] @ B[K,256] + bias)
// A: [.][K] (bf16 or fp32). Bt: bf16 [256][K] pre-transposed. bias fp32.
// Block = 4 waves = 64 rows x 256 cols; wave w = 64 rows x 64 cols via 4x4
// of 16x16x32 MFMA. K-loop alternates two chunk-register-buffers so the next
// chunk's 8 global loads are always in flight behind the current 16 MFMAs.
// ---------------------------------------------------------------------------
template <int K, typename AT, bool BIAS, bool RELU, bool OUTF32>
__global__ __launch_bounds__(256) void gemm_nolds_k(
    const AT* __restrict__ A, const unsigned short* __restrict__ Bt,
    const float* __restrict__ bias, void* __restrict__ C, int M) {
    const int lane = threadIdx.x & 63;
    const int wid = threadIdx.x >> 6;
    const int col0 = wid * 64;
    const int rowbase = blockIdx.y * 64;
    const int r15 = lane & 15;
    const int kq = lane >> 4;  // 0..3

    const AT* aptr[4];
#pragma unroll
    for (int i = 0; i < 4; ++i) {
        int row = rowbase + i * 16 + r15;
        if (row > M - 1) row = M - 1;  // clamp: no OOB reads
        aptr[i] = A + (size_t)row * K + kq * 8;
    }
    const unsigned short* bptr[4];
#pragma unroll
    for (int j = 0; j < 4; ++j)
        bptr[j] = Bt + (size_t)(col0 + j * 16 + r15) * K + kq * 8;

    f32x4 acc[4][4] = {};
    bf16x8 a0[4], b0[4], a1[4], b1[4];

    // prologue: chunk 0 into buffer 0
#pragma unroll
    for (int i = 0; i < 4; ++i) a0[i] = loadA(aptr[i]);
#pragma unroll
    for (int j = 0; j < 4; ++j) b0[j] = *((const bf16x8*)(bptr[j]));

#pragma unroll
    for (int k0 = 0; k0 < K; k0 += 64) {
        // prefetch chunk k0+32 into buffer 1
#pragma unroll
        for (int i = 0; i < 4; ++i) a1[i] = loadA(aptr[i] + k0 + 32);
#pragma unroll
        for (int j = 0; j < 4; ++j) b1[j] = *((const bf16x8*)(bptr[j] + k0 + 32));
        // compute chunk k0 from buffer 0
#pragma unroll
        for (int i = 0; i < 4; ++i)
#pragma unroll
            for (int j = 0; j < 4; ++j)
                acc[i][j] = __builtin_amdgcn_mfma_f32_16x16x32_bf16(a0[i], b0[j], acc[i][j], 0, 0, 0);
        // prefetch chunk k0+64 into buffer 0
        if (k0 + 64 < K) {
#pragma unroll
            for (int i = 0; i < 4; ++i) a0[i] = loadA(aptr[i] + k0 + 64);
#pragma unroll
            for (int j = 0; j < 4; ++j) b0[j] = *((const bf16x8*)(bptr[j] + k0 + 64));
        }
        // compute chunk k0+32 from buffer 1
#pragma unroll
        for (int i = 0; i < 4; ++i)
#pragma unroll
            for (int j = 0; j < 4; ++j)
                acc[i][j] = __builtin_amdgcn_mfma_f32_16x16x32_bf16(a1[i], b1[j], acc[i][j], 0, 0, 0);
    }

    // Epilogue: C/D layout col=lane&15, row=(lane>>4)*4+reg
#pragma unroll
    for (int i = 0; i < 4; ++i) {
#pragma unroll
        for (int reg = 0; reg < 4; ++reg) {
            int row = rowbase + i * 16 + (lane >> 4) * 4 + reg;
            if (row >= M) continue;
#pragma unroll
            for (int j = 0; j < 4; ++j) {
                int col = col0 + j * 16 + (lane & 15);
                float v = acc[i][j][reg];
                if (BIAS) v += bias[col];
                if (RELU) v = fmaxf(v, 0.0f);
                if (OUTF32)
                    ((float*)C)[(size_t)row * HDIM + col] = v;
                else
                    ((unsigned short*)C)[(size_t)row * HDIM + col] = f2bf(v);
            }
        }
    }
}

// ---------------------------------------------------------------------------
// Weight prep: W[nm][K][256] fp32 -> Wt[nm][256][K] bf16 (transpose+convert)
// ---------------------------------------------------------------------------
__global__ void wprep_k(const float* __restrict__ W, unsigned short* __restrict__ Wt,
                        int K, int total) {
    int i = blockIdx.x * blockDim.x + threadIdx.x;
    if (i >= total) return;
    int mat = i / (K * 256);
    int r = i - mat * (K * 256);
    int k = r >> 8, p = r & 255;
    Wt[(size_t)mat * K * 256 + (size_t)p * K + k] = f2bf(W[i]);
}

// Straight fp32 -> bf16 convert (no transpose), vectorized x4
__global__ void conv_k(const float* __restrict__ W, unsigned short* __restrict__ o, int n4) {
    int i = blockIdx.x * blockDim.x + threadIdx.x;
    if (i >= n4) return;
    float4 v = ((const float4*)W)[i];
    ushort4 u;
    u.x = f2bf(v.x); u.y = f2bf(v.y); u.z = f2bf(v.z); u.w = f2bf(v.w);
    ((ushort4*)o)[i] = u;
}

// foldb[c] = sum_j b2[j] * G0[j][c]   (G0 = gcn_w layer 0, row-major fp32)
__global__ void foldbias_k(const float* __restrict__ b2, const float* __restrict__ g0,
                           float* __restrict__ fb) {
    int c = threadIdx.x;  // one block of 256
    float s = 0.0f;
#pragma unroll 8
    for (int j = 0; j < HDIM; ++j) s += b2[j] * g0[(size_t)j * HDIM + c];
    fb[c] = s;
}

// ---------------------------------------------------------------------------
// CSR build utilities
// ---------------------------------------------------------------------------
__global__ void zero_k(unsigned* __restrict__ p, int n) {
    int i = blockIdx.x * blockDim.x + threadIdx.x;
    if (i < n) p[i] = 0u;
}

__global__ void count_k(const int* __restrict__ dst, unsigned* __restrict__ cnt, int E) {
    int e = blockIdx.x * blockDim.x + threadIdx.x;
    if (e < E) atomicAdd(&cnt[dst[e]], 1u);
}

// scan1 also computes dinv and zeroes cnt (cursor reuse) — saves 2 launches
__global__ __launch_bounds__(256) void scan1_k(unsigned* __restrict__ cnt,
                                               int* __restrict__ rs,
                                               unsigned* __restrict__ blocksum,
                                               float* __restrict__ dinv, int N) {
    __shared__ unsigned tmp[256];
    int tid = threadIdx.x;
    int gid = blockIdx.x * 256 + tid;
    unsigned v = (gid < N) ? cnt[gid] : 0u;
    if (gid < N) {
        dinv[gid] = 1.0f / sqrtf((float)(v + 1u));  // +1 = self loop
        cnt[gid] = 0u;                               // reset for cursor use
    }
    tmp[tid] = v;
    __syncthreads();
#pragma unroll
    for (int off = 1; off < 256; off <<= 1) {
        unsigned t = (tid >= off) ? tmp[tid - off] : 0u;
        __syncthreads();
        tmp[tid] += t;
        __syncthreads();
    }
    if (gid < N) rs[gid] = (int)(tmp[tid] - v);
    if (tid == 255) blocksum[blockIdx.x] = tmp[tid];
}

__global__ __launch_bounds__(512) void scan2_k(unsigned* __restrict__ blocksum, int nb) {
    __shared__ unsigned tmp[512];
    int tid = threadIdx.x;
    unsigned v = (tid < nb) ? blocksum[tid] : 0u;
    tmp[tid] = v;
    __syncthreads();
#pragma unroll
    for (int off = 1; off < 512; off <<= 1) {
        unsigned t = (tid >= off) ? tmp[tid - off] : 0u;
        __syncthreads();
        tmp[tid] += t;
        __syncthreads();
    }
    if (tid < nb) blocksum[tid] = tmp[tid] - v;
}

__global__ void scan3_k(int* __restrict__ rs, const unsigned* __restrict__ blocksum, int N, int E) {
    int gid = blockIdx.x * blockDim.x + threadIdx.x;
    if (gid < N) rs[gid] += (int)blocksum[gid >> 8];
    if (gid == 0) rs[N] = E;
}

__global__ void fill_k(const int* __restrict__ src, const int* __restrict__ dst,
                       const int* __restrict__ rs, unsigned* __restrict__ cursor,
                       const float* __restrict__ dinv,
                       int* __restrict__ srcs, float* __restrict__ ww, int E) {
    int e = blockIdx.x * blockDim.x + threadIdx.x;
    if (e >= E) return;
    int s = src[e], d = dst[e];
    int pos = rs[d] + (int)atomicAdd(&cursor[d], 1u);
    srcs[pos] = s;
    ww[pos] = dinv[s] * dinv[d];
}

// ---------------------------------------------------------------------------
// CSR gather-aggregate (bf16 m), fused self-loop + bias + ReLU.
// One wave per node; ushort4 (4 cols) per lane.
// ---------------------------------------------------------------------------
template <bool OUTF32>
__global__ __launch_bounds__(256) void gather_k(const int* __restrict__ rs,
                                                const int* __restrict__ srcs,
                                                const float* __restrict__ ww,
                                                const float* __restrict__ dinv,
                                                const unsigned short* __restrict__ m,
                                                const float* __restrict__ bias,
                                                void* __restrict__ out, int N) {
    int node = blockIdx.x * 4 + (threadIdx.x >> 6);
    int lane = threadIdx.x & 63;
    if (node >= N) return;
    int beg = rs[node], end = rs[node + 1];
    float d = dinv[node];
    float w0 = d * d;
    ushort4 u = ((const ushort4*)(m + (size_t)node * HDIM))[lane];
    float ax = bf2f(u.x) * w0, ay = bf2f(u.y) * w0, az = bf2f(u.z) * w0, aw = bf2f(u.w) * w0;
    for (int e = beg; e < end; ++e) {
        int s = srcs[e];
        float w = ww[e];
        ushort4 v = ((const ushort4*)(m + (size_t)s * HDIM))[lane];
        ax += bf2f(v.x) * w;
        ay += bf2f(v.y) * w;
        az += bf2f(v.z) * w;
        aw += bf2f(v.w) * w;
    }
    float4 b = ((const float4*)bias)[lane];
    ax = fmaxf(ax + b.x, 0.0f);
    ay = fmaxf(ay + b.y, 0.0f);
    az = fmaxf(az + b.z, 0.0f);
    aw = fmaxf(aw + b.w, 0.0f);
    if (OUTF32) {
        float4 o = {ax, ay, az, aw};
        ((float4*)out)[(size_t)node * 64 + lane] = o;
    } else {
        ushort4 o;
        o.x = f2bf(ax); o.y = f2bf(ay); o.z = f2bf(az); o.w = f2bf(aw);
        ((ushort4*)out)[(size_t)node * 64 + lane] = o;
    }
}

extern "C" void kernel_launch(void* const* d_in, const int* in_sizes, int n_in,
                              void* d_out, int out_size, void* d_ws, size_t ws_size,
                              hipStream_t stream) {
    const float* x  = (const float*)d_in[0];
    const int* ei   = (const int*)d_in[1];
    const float* w1 = (const float*)d_in[2];
    const float* b1 = (const float*)d_in[3];
    const float* w2 = (const float*)d_in[4];
    const float* b2 = (const float*)d_in[5];
    const float* gw = (const float*)d_in[6];
    const float* gb = (const float*)d_in[7];

    const int N = NNODES, E = NEDGES;
    const int* src = ei;
    const int* dst = ei + E;

    // Workspace layout (~158 MB)
    char* p = (char*)d_ws;
    unsigned short* h1   = (unsigned short*)p; p += (size_t)MPAD * HDIM * 2;  // 51.2 MB
    unsigned short* h    = (unsigned short*)p; p += (size_t)MPAD * HDIM * 2;
    unsigned short* m    = (unsigned short*)p; p += (size_t)MPAD * HDIM * 2;
    unsigned short* w1t  = (unsigned short*)p; p += (size_t)FIN * HDIM * 2;
    unsigned short* gwt  = (unsigned short*)p; p += (size_t)NLAYERS * HDIM * HDIM * 2;
    unsigned short* w2c  = (unsigned short*)p; p += (size_t)HDIM * HDIM * 2;   // w2 bf16 row-major
    unsigned short* fBt  = (unsigned short*)p; p += (size_t)HDIM * HDIM * 2;   // folded W2*G0, Bt layout
    float* foldb = (float*)p;          p += (size_t)HDIM * 4;                  // folded bias b2*G0
    unsigned* cnt = (unsigned*)p;      p += (size_t)N * 4;
    float* dinv = (float*)p;           p += (size_t)N * 4;
    int* rs = (int*)p;                 p += (size_t)(N + 1) * 4 + 12;
    unsigned* blocksum = (unsigned*)p; p += 512 * 4;
    int* srcs = (int*)p;               p += (size_t)E * 4;
    float* wwt = (float*)p;            p += (size_t)E * 4;

    const int nb = (N + 255) / 256;             // 391
    const dim3 ggrid(1, MPAD / 64);             // 1564 blocks, 4 waves each

    // ---- Weight conversion ----
    wprep_k<<<(FIN * 256 + 255) / 256, 256, 0, stream>>>(w1, w1t, FIN, FIN * 256);
    wprep_k<<<(NLAYERS * HDIM * 256 + 255) / 256, 256, 0, stream>>>(gw, gwt, HDIM, NLAYERS * HDIM * 256);
    conv_k<<<(HDIM * HDIM / 4 + 255) / 256, 256, 0, stream>>>(w2, w2c, HDIM * HDIM / 4);

    // ---- Fold: fBt[c][k'] = sum_j G0[j][c]*W2[k'][j];  foldb[c] = sum_j b2[j]*G0[j][c]
    // gemm_nolds computes C[m][p] = sum_k A[m][k]*Bt[p][k]; A=gwt0 (gwt0[c][j]=G0[j][c]),
    // Bt=w2c row-major (w2c[k'][j]=W2[k'][j]) -> C[c][k'] = fold ✓
    foldbias_k<<<1, 256, 0, stream>>>(b2, gw, foldb);
    gemm_nolds_k<HDIM, unsigned short, false, false, false><<<dim3(1, 4), 256, 0, stream>>>(
        gwt, w2c, nullptr, fBt, HDIM);

    // ---- CSR build (6 launches) ----
    zero_k<<<nb, 256, 0, stream>>>(cnt, N);
    count_k<<<(E + 255) / 256, 256, 0, stream>>>(dst, cnt, E);
    scan1_k<<<nb, 256, 0, stream>>>(cnt, rs, blocksum, dinv, N);
    scan2_k<<<1, 512, 0, stream>>>(blocksum, nb);
    scan3_k<<<nb + 1, 256, 0, stream>>>(rs, blocksum, N, E);
    fill_k<<<(E + 255) / 256, 256, 0, stream>>>(src, dst, rs, cnt, dinv, srcs, wwt, E);

    // ---- Encoder GEMM1 (x fp32 loads + in-register bf16 pack) ----
    gemm_nolds_k<FIN, float, true, true, false><<<ggrid, 256, 0, stream>>>(x, w1t, b1, h1, N);

    // ---- Layer 0 (folded): m = h1 @ (W2*G0) + b2*G0 ----
    gemm_nolds_k<HDIM, unsigned short, true, false, false><<<ggrid, 256, 0, stream>>>(h1, fBt, foldb, m, N);
    gather_k<false><<<(N + 3) / 4, 256, 0, stream>>>(rs, srcs, wwt, dinv, m, gb, h, N);

    // ---- Layers 1..2 ----
    for (int l = 1; l < NLAYERS; ++l) {
        const unsigned short* wl = gwt + (size_t)l * HDIM * HDIM;
        const float* bl = gb + (size_t)l * HDIM;
        gemm_nolds_k<HDIM, unsigned short, false, false, false><<<ggrid, 256, 0, stream>>>(h, wl, nullptr, m, N);
        if (l < NLAYERS - 1)
            gather_k<false><<<(N + 3) / 4, 256, 0, stream>>>(rs, srcs, wwt, dinv, m, bl, h, N);
        else
            gather_k<true><<<(N + 3) / 4, 256, 0, stream>>>(rs, srcs, wwt, dinv, m, bl, d_out, N);
    }
}